// Round 3
// baseline (396.255 us; speedup 1.0000x reference)
//
#include <hip/hip_runtime.h>

#define Bc 2
#define Sc 2048
#define Hc 2048
#define NHc 16
#define HDc 128
#define SLOTSc 16
#define NROWS (Bc * Sc)   // 4096

// ---------------------------------------------------------------------------
// Kernel 1: actions = softmax( (hidden @ W_action^T + b) / sqrt(128) )
// Block = 256 thr = 4 waves = 64 outputs (4 rows x 16 heads) x 4 K-chunks.
// Thread (o, kc): o = tid&63 -> (row_local = o>>4, head = o&15), kc = tid>>6.
// Each thread dots 512 elements; LDS combine over kc; thread o finishes
// softmax-3. Grid = 1024 blocks = 4096 waves (16/CU).
// ---------------------------------------------------------------------------
__global__ __launch_bounds__(256) void actions_kernel(
    const float* __restrict__ hidden,    // [4096][2048]
    const float* __restrict__ W_action,  // [48][2048]
    const float* __restrict__ b_action,  // [48]
    float* __restrict__ actions)         // [4096][16][3]
{
    __shared__ float part[3][4][64];

    const int tid  = threadIdx.x;
    const int o    = tid & 63;
    const int kc   = tid >> 6;
    const int rl   = o >> 4;
    const int head = o & 15;
    const int r    = blockIdx.x * 4 + rl;
    const int c0   = 3 * head;

    const float4* A  = (const float4*)(hidden + (size_t)r * Hc + kc * 512);
    const float4* B0 = (const float4*)(W_action + (size_t)c0 * Hc + kc * 512);
    const float4* B1 = B0 + (Hc / 4);
    const float4* B2 = B1 + (Hc / 4);

    float s0 = 0.f, s1 = 0.f, s2 = 0.f;
    #pragma unroll 8
    for (int j = 0; j < 128; ++j) {
        float4 a  = A[j];
        float4 b0 = B0[j];
        float4 b1 = B1[j];
        float4 b2 = B2[j];
        s0 = fmaf(a.x, b0.x, fmaf(a.y, b0.y, fmaf(a.z, b0.z, fmaf(a.w, b0.w, s0))));
        s1 = fmaf(a.x, b1.x, fmaf(a.y, b1.y, fmaf(a.z, b1.z, fmaf(a.w, b1.w, s1))));
        s2 = fmaf(a.x, b2.x, fmaf(a.y, b2.y, fmaf(a.z, b2.z, fmaf(a.w, b2.w, s2))));
    }
    part[0][kc][o] = s0;
    part[1][kc][o] = s1;
    part[2][kc][o] = s2;
    __syncthreads();

    if (tid < 64) {
        float t0 = part[0][0][o] + part[0][1][o] + part[0][2][o] + part[0][3][o];
        float t1 = part[1][0][o] + part[1][1][o] + part[1][2][o] + part[1][3][o];
        float t2 = part[2][0][o] + part[2][1][o] + part[2][2][o] + part[2][3][o];
        const float scale = 0.08838834764831845f; // 1/sqrt(128)
        float l0 = (t0 + b_action[c0 + 0]) * scale;
        float l1 = (t1 + b_action[c0 + 1]) * scale;
        float l2 = (t2 + b_action[c0 + 2]) * scale;
        float lm = fmaxf(l0, fmaxf(l1, l2));
        float e0 = __expf(l0 - lm), e1 = __expf(l1 - lm), e2 = __expf(l2 - lm);
        float inv = 1.f / (e0 + e1 + e2);
        float* ap = actions + ((size_t)r * NHc + head) * 3;
        ap[0] = e0 * inv;
        ap[1] = e1 * inv;
        ap[2] = e2 * inv;
    }
}

// ---------------------------------------------------------------------------
// Kernel 2: pure streaming, one independent wave per (b,s,head). No LDS, no
// __syncthreads. Lane l owns dims 2l,2l+1. Gate reduction = merge-butterfly
// reduce-scatter (17 shuffles; slot k's sum lands at lanes with lane&15==k),
// softmax in distributed form (1 exp), gate weights re-broadcast via 16
// ds_bpermute for the weighted sum.
// ---------------------------------------------------------------------------
__global__ __launch_bounds__(256, 5) void stack_stream(
    const float* __restrict__ hidden,     // [4096][2048]
    const float* __restrict__ stack,      // [4096][16][16][128]
    const float* __restrict__ mask,       // [4096][16][16]
    const float* __restrict__ actions,    // [4096][16][3]
    const float* __restrict__ W_gate,     // [128]
    const float* __restrict__ b_gate,     // [1]
    const float* __restrict__ res_weight, // [1]
    float* __restrict__ out,              // [4096][2048]
    float* __restrict__ new_stack,        // [4096][16][16][128]
    float* __restrict__ new_mask)         // [4096][16][16]
{
    const int bs   = blockIdx.x >> 2;
    const int hg   = blockIdx.x & 3;
    const int lane = threadIdx.x & 63;
    const int wave = threadIdx.x >> 6;
    const int n    = hg * 4 + wave;

    const float* ap = actions + ((size_t)bs * NHc + n) * 3;
    const float a_push = ap[0];
    const float a_pop  = ap[1];
    const float a_stay = ap[2];

    const size_t sbase = ((size_t)bs * NHc + n) * (size_t)(SLOTSc * HDc);
    const float2* st2  = (const float2*)(stack + sbase);
    float2*       nst2 = (float2*)(new_stack + sbase);

    float2 kv = *(const float2*)(hidden + (size_t)bs * Hc + n * HDc + 2 * lane);
    float2 wg = *(const float2*)(W_gate + 2 * lane);
    const float bg = b_gate[0];
    const float rw = res_weight[0];

    // ---- distributed mask: lane l holds mask[cls], cls = l&15 ----
    const int cls  = lane & 15;
    const int grp  = lane & 48;
    const float* mp = mask + ((size_t)bs * NHc + n) * SLOTSc;
    float m_d = mp[cls];
    {
        // neighbors via bpermute within the 16-lane group
        int ap_prev = (grp | (cls == 0 ? 0 : cls - 1)) << 2;
        int ap_next = (grp | (cls == 15 ? 15 : cls + 1)) << 2;
        float m_prev = __int_as_float(__builtin_amdgcn_ds_bpermute(ap_prev, __float_as_int(m_d)));
        float m_next = __int_as_float(__builtin_amdgcn_ds_bpermute(ap_next, __float_as_int(m_d)));
        m_prev = (cls == 0)  ? 1.f : m_prev;
        m_next = (cls == 15) ? 0.f : m_next;
        m_d = a_push * m_prev + a_pop * m_next + a_stay * m_d;  // m_d is now nm_dist
    }
    if (lane < SLOTSc)
        new_mask[((size_t)bs * NHc + n) * SLOTSc + lane] = m_d;

    // ---- new_stack: rolling window; gate partials p[k] per lane ----
    float2 ns[SLOTSc];
    float  p[SLOTSc];
    {
        float2 prev = kv;
        float2 cur  = st2[lane];
        #pragma unroll
        for (int k = 0; k < SLOTSc; ++k) {
            float2 nxt;
            if (k < SLOTSc - 1) nxt = st2[(k + 1) * 64 + lane];
            else { nxt.x = 0.f; nxt.y = 0.f; }
            ns[k].x = a_push * prev.x + a_pop * nxt.x + a_stay * cur.x;
            ns[k].y = a_push * prev.y + a_pop * nxt.y + a_stay * cur.y;
            nst2[k * 64 + lane] = ns[k];
            p[k] = ns[k].x * wg.x + ns[k].y * wg.y;
            prev = cur; cur = nxt;
        }
    }

    // ---- merge-butterfly reduce-scatter: S[l&15] in u ----
    float w8[8];
    #pragma unroll
    for (int j = 0; j < 8; ++j) {
        float a = p[2 * j], b = p[2 * j + 1];
        bool hi = (lane & 1);
        float keep = hi ? b : a;
        float send = hi ? a : b;
        w8[j] = keep + __shfl_xor(send, 1, 64);
    }
    float w4[4];
    #pragma unroll
    for (int j = 0; j < 4; ++j) {
        float a = w8[2 * j], b = w8[2 * j + 1];
        bool hi = (lane & 2);
        float keep = hi ? b : a;
        float send = hi ? a : b;
        w4[j] = keep + __shfl_xor(send, 2, 64);
    }
    float w2[2];
    #pragma unroll
    for (int j = 0; j < 2; ++j) {
        float a = w4[2 * j], b = w4[2 * j + 1];
        bool hi = (lane & 4);
        float keep = hi ? b : a;
        float send = hi ? a : b;
        w2[j] = keep + __shfl_xor(send, 4, 64);
    }
    float u;
    {
        float a = w2[0], b = w2[1];
        bool hi = (lane & 8);
        float keep = hi ? b : a;
        float send = hi ? a : b;
        u = keep + __shfl_xor(send, 8, 64);
    }
    u += __shfl_xor(u, 16, 64);
    u += __shfl_xor(u, 32, 64);
    // u = dot(ns[l&15], W_gate) summed over all 128 dims

    // ---- distributed masked softmax over the 16 classes ----
    float g = u + bg + (1.f - m_d) * -1000000000.0f;
    float mx = g;
    mx = fmaxf(mx, __shfl_xor(mx, 1, 64));
    mx = fmaxf(mx, __shfl_xor(mx, 2, 64));
    mx = fmaxf(mx, __shfl_xor(mx, 4, 64));
    mx = fmaxf(mx, __shfl_xor(mx, 8, 64));
    float e = __expf(g - mx);
    float ssum = e;
    ssum += __shfl_xor(ssum, 1, 64);
    ssum += __shfl_xor(ssum, 2, 64);
    ssum += __shfl_xor(ssum, 4, 64);
    ssum += __shfl_xor(ssum, 8, 64);
    float gw_d = e / ssum;   // gate weight for slot l&15

    // ---- broadcast gw[k] to all lanes; weighted sum + residual ----
    float2 mo; mo.x = 0.f; mo.y = 0.f;
    const int grpb = grp << 2;
    #pragma unroll
    for (int k = 0; k < SLOTSc; ++k) {
        float gwk = __int_as_float(
            __builtin_amdgcn_ds_bpermute(grpb | (k << 2), __float_as_int(gw_d)));
        mo.x = fmaf(gwk, ns[k].x, mo.x);
        mo.y = fmaf(gwk, ns[k].y, mo.y);
    }
    float2 ov;
    ov.x = mo.x * rw + kv.x;
    ov.y = mo.y * rw + kv.y;
    *(float2*)(out + (size_t)bs * Hc + n * HDc + 2 * lane) = ov;
}

extern "C" void kernel_launch(void* const* d_in, const int* in_sizes, int n_in,
                              void* d_out, int out_size, void* d_ws, size_t ws_size,
                              hipStream_t stream) {
    const float* hidden     = (const float*)d_in[0];
    const float* stack      = (const float*)d_in[1];
    const float* mask       = (const float*)d_in[2];
    const float* W_action   = (const float*)d_in[3];
    const float* b_action   = (const float*)d_in[4];
    const float* W_gate     = (const float*)d_in[5];
    const float* b_gate     = (const float*)d_in[6];
    const float* res_weight = (const float*)d_in[7];

    float* out       = (float*)d_out;
    float* new_stack = out + (size_t)Bc * Sc * Hc;
    float* new_mask  = new_stack + (size_t)Bc * Sc * NHc * SLOTSc * HDc;

    float* actions = (float*)d_ws; // 4096*16*3*4 = 786,432 B

    hipLaunchKernelGGL(actions_kernel, dim3(NROWS / 4), dim3(256), 0, stream,
                       hidden, W_action, b_action, actions);

    hipLaunchKernelGGL(stack_stream, dim3(NROWS * 4), dim3(256), 0, stream,
                       hidden, stack, mask, actions, W_gate, b_gate, res_weight,
                       out, new_stack, new_mask);
}

// Round 4
// 267.215 us; speedup vs baseline: 1.4829x; 1.4829x over previous
//
#include <hip/hip_runtime.h>

#define Bc 2
#define Sc 2048
#define Hc 2048
#define NHc 16
#define HDc 128
#define SLOTSc 16
#define NROWS (Bc * Sc)   // 4096

// ---------------------------------------------------------------------------
// Single fused kernel. One INDEPENDENT wave per (b,s,head): no LDS, no
// __syncthreads — waves at different phases co-schedule, so the per-wave
// GEMV (L2-bound) and slot-softmax (DS ops) hide under the 1.1 GB HBM
// stream. Lane l owns dims 2l,2l+1 of its head (float2, 8B/lane coalesced).
//
// Phases per wave:
//   1. issue 16 stack float2 loads (HBM stream, in-flight during GEMV)
//   2. GEMV: 3 action logits = dot(hidden_row, W_action rows 3n..3n+2),
//      fully coalesced float4 loads, 18-shuffle reduce, softmax-3
//   3. new_stack/new_mask compute + stores; gate partials
//   4. distributed gate reduce (merge-butterfly reduce-scatter: slot k's
//      score lands on lanes with lane&15==k), distributed masked softmax
//      (1 exp), bpermute-broadcast weighted sum, residual, store out.
// ---------------------------------------------------------------------------
__global__ __launch_bounds__(256, 4) void stack_fused(
    const float* __restrict__ hidden,     // [4096][2048]
    const float* __restrict__ stack,      // [4096][16][16][128]
    const float* __restrict__ mask,       // [4096][16][16]
    const float* __restrict__ W_action,   // [48][2048]
    const float* __restrict__ b_action,   // [48]
    const float* __restrict__ W_gate,     // [128]
    const float* __restrict__ b_gate,     // [1]
    const float* __restrict__ res_weight, // [1]
    float* __restrict__ out,              // [4096][2048]
    float* __restrict__ new_stack,        // [4096][16][16][128]
    float* __restrict__ new_mask)         // [4096][16][16]
{
    const int bs   = blockIdx.x >> 2;
    const int hg   = blockIdx.x & 3;
    const int lane = threadIdx.x & 63;
    const int wave = threadIdx.x >> 6;
    const int n    = hg * 4 + wave;

    // ---- phase 1: issue the stack stream loads first (oldest in queue) ----
    const size_t sbase = ((size_t)bs * NHc + n) * (size_t)(SLOTSc * HDc);
    const float2* st2  = (const float2*)(stack + sbase);
    float2 sv[SLOTSc];
    #pragma unroll
    for (int k = 0; k < SLOTSc; ++k) sv[k] = st2[k * 64 + lane];

    float2 kv = *(const float2*)(hidden + (size_t)bs * Hc + n * HDc + 2 * lane);
    float2 wg = *(const float2*)(W_gate + 2 * lane);

    // ---- distributed mask: lane l holds mask[l&15] ----
    const int cls = lane & 15;
    const int grp = lane & 48;
    float m_d = mask[((size_t)bs * NHc + n) * SLOTSc + cls];

    // ---- phase 2: GEMV for this head's 3 logits (coalesced) ----
    float s0 = 0.f, s1 = 0.f, s2 = 0.f;
    {
        const float4* hp = (const float4*)(hidden + (size_t)bs * Hc);
        const float4* W0 = (const float4*)(W_action + (size_t)(3 * n) * Hc);
        const float4* W1 = W0 + (Hc / 4);
        const float4* W2 = W1 + (Hc / 4);
        #pragma unroll
        for (int j = 0; j < 8; ++j) {
            float4 a  = hp[lane + j * 64];
            float4 b0 = W0[lane + j * 64];
            float4 b1 = W1[lane + j * 64];
            float4 b2 = W2[lane + j * 64];
            s0 = fmaf(a.x, b0.x, fmaf(a.y, b0.y, fmaf(a.z, b0.z, fmaf(a.w, b0.w, s0))));
            s1 = fmaf(a.x, b1.x, fmaf(a.y, b1.y, fmaf(a.z, b1.z, fmaf(a.w, b1.w, s1))));
            s2 = fmaf(a.x, b2.x, fmaf(a.y, b2.y, fmaf(a.z, b2.z, fmaf(a.w, b2.w, s2))));
        }
    }
    #pragma unroll
    for (int o = 32; o; o >>= 1) {
        s0 += __shfl_xor(s0, o, 64);
        s1 += __shfl_xor(s1, o, 64);
        s2 += __shfl_xor(s2, o, 64);
    }
    const float scale = 0.08838834764831845f; // 1/sqrt(128)
    float l0 = (s0 + b_action[3 * n + 0]) * scale;
    float l1 = (s1 + b_action[3 * n + 1]) * scale;
    float l2 = (s2 + b_action[3 * n + 2]) * scale;
    float lm = fmaxf(l0, fmaxf(l1, l2));
    float e0 = __expf(l0 - lm), e1 = __expf(l1 - lm), e2 = __expf(l2 - lm);
    float inv3 = 1.f / (e0 + e1 + e2);
    const float a_push = e0 * inv3;
    const float a_pop  = e1 * inv3;
    const float a_stay = e2 * inv3;

    // ---- new_mask (distributed) ----
    {
        int ap_prev = (grp | (cls == 0 ? 0 : cls - 1)) << 2;
        int ap_next = (grp | (cls == 15 ? 15 : cls + 1)) << 2;
        float m_prev = __int_as_float(__builtin_amdgcn_ds_bpermute(ap_prev, __float_as_int(m_d)));
        float m_next = __int_as_float(__builtin_amdgcn_ds_bpermute(ap_next, __float_as_int(m_d)));
        m_prev = (cls == 0)  ? 1.f : m_prev;
        m_next = (cls == 15) ? 0.f : m_next;
        m_d = a_push * m_prev + a_pop * m_next + a_stay * m_d;  // now new_mask
    }
    if (lane < SLOTSc)
        new_mask[((size_t)bs * NHc + n) * SLOTSc + lane] = m_d;

    // ---- phase 3: new_stack (in-place into sv) + gate partials + stores ----
    const float bg = b_gate[0];
    const float rw = res_weight[0];
    float2* nst2 = (float2*)(new_stack + sbase);
    float p[SLOTSc];
    {
        float2 prev = kv;
        #pragma unroll
        for (int k = 0; k < SLOTSc; ++k) {
            float2 cur = sv[k];
            float2 nxt;
            if (k < SLOTSc - 1) nxt = sv[k + 1];
            else { nxt.x = 0.f; nxt.y = 0.f; }
            float2 ns;
            ns.x = a_push * prev.x + a_pop * nxt.x + a_stay * cur.x;
            ns.y = a_push * prev.y + a_pop * nxt.y + a_stay * cur.y;
            sv[k] = ns;
            nst2[k * 64 + lane] = ns;
            p[k] = ns.x * wg.x + ns.y * wg.y;
            prev = cur;
        }
    }

    // ---- phase 4a: merge-butterfly reduce-scatter (slot k -> lanes l&15==k) ----
    float w8[8];
    #pragma unroll
    for (int j = 0; j < 8; ++j) {
        float a = p[2 * j], b = p[2 * j + 1];
        bool hi = (lane & 1);
        float keep = hi ? b : a;
        float send = hi ? a : b;
        w8[j] = keep + __shfl_xor(send, 1, 64);
    }
    float w4[4];
    #pragma unroll
    for (int j = 0; j < 4; ++j) {
        float a = w8[2 * j], b = w8[2 * j + 1];
        bool hi = (lane & 2);
        float keep = hi ? b : a;
        float send = hi ? a : b;
        w4[j] = keep + __shfl_xor(send, 2, 64);
    }
    float w2[2];
    #pragma unroll
    for (int j = 0; j < 2; ++j) {
        float a = w4[2 * j], b = w4[2 * j + 1];
        bool hi = (lane & 4);
        float keep = hi ? b : a;
        float send = hi ? a : b;
        w2[j] = keep + __shfl_xor(send, 4, 64);
    }
    float u;
    {
        float a = w2[0], b = w2[1];
        bool hi = (lane & 8);
        float keep = hi ? b : a;
        float send = hi ? a : b;
        u = keep + __shfl_xor(send, 8, 64);
    }
    u += __shfl_xor(u, 16, 64);
    u += __shfl_xor(u, 32, 64);
    // u = dot(new_stack[l&15], W_gate) over all 128 dims

    // ---- phase 4b: distributed masked softmax over 16 slots ----
    float g = u + bg + (1.f - m_d) * -1000000000.0f;
    float mx = g;
    mx = fmaxf(mx, __shfl_xor(mx, 1, 64));
    mx = fmaxf(mx, __shfl_xor(mx, 2, 64));
    mx = fmaxf(mx, __shfl_xor(mx, 4, 64));
    mx = fmaxf(mx, __shfl_xor(mx, 8, 64));
    float e = __expf(g - mx);
    float ssum = e;
    ssum += __shfl_xor(ssum, 1, 64);
    ssum += __shfl_xor(ssum, 2, 64);
    ssum += __shfl_xor(ssum, 4, 64);
    ssum += __shfl_xor(ssum, 8, 64);
    float gw_d = e / ssum;   // gate weight for slot l&15

    // ---- phase 4c: broadcast gate weights; weighted sum + residual ----
    float2 mo; mo.x = 0.f; mo.y = 0.f;
    const int grpb = grp << 2;
    #pragma unroll
    for (int k = 0; k < SLOTSc; ++k) {
        float gwk = __int_as_float(
            __builtin_amdgcn_ds_bpermute(grpb | (k << 2), __float_as_int(gw_d)));
        mo.x = fmaf(gwk, sv[k].x, mo.x);
        mo.y = fmaf(gwk, sv[k].y, mo.y);
    }
    float2 ov;
    ov.x = mo.x * rw + kv.x;
    ov.y = mo.y * rw + kv.y;
    *(float2*)(out + (size_t)bs * Hc + n * HDc + 2 * lane) = ov;
}

extern "C" void kernel_launch(void* const* d_in, const int* in_sizes, int n_in,
                              void* d_out, int out_size, void* d_ws, size_t ws_size,
                              hipStream_t stream) {
    const float* hidden     = (const float*)d_in[0];
    const float* stack      = (const float*)d_in[1];
    const float* mask       = (const float*)d_in[2];
    const float* W_action   = (const float*)d_in[3];
    const float* b_action   = (const float*)d_in[4];
    const float* W_gate     = (const float*)d_in[5];
    const float* b_gate     = (const float*)d_in[6];
    const float* res_weight = (const float*)d_in[7];

    float* out       = (float*)d_out;
    float* new_stack = out + (size_t)Bc * Sc * Hc;
    float* new_mask  = new_stack + (size_t)Bc * Sc * NHc * SLOTSc * HDc;

    hipLaunchKernelGGL(stack_fused, dim3(NROWS * 4), dim3(256), 0, stream,
                       hidden, stack, mask, W_action, b_action,
                       W_gate, b_gate, res_weight,
                       out, new_stack, new_mask);
}

// Round 5
// 225.872 us; speedup vs baseline: 1.7543x; 1.1830x over previous
//
#include <hip/hip_runtime.h>

#define Bc 2
#define Sc 2048
#define Hc 2048
#define NHc 16
#define HDc 128
#define SLOTSc 16
#define NROWS (Bc * Sc)   // 4096

// ---------------------------------------------------------------------------
// Fused kernel, R1 structure + vectorized GEMV + early stream start.
// Block = 512 thr = 8 waves = 8 heads of one (b,s) row; grid = NROWS*2.
// Lane l owns dims 2l,2l+1 of its head (float2, 8B/lane coalesced).
//
// Per block:
//   0. issue hidden-row staging load (float4/thread) AND each wave's 16
//      stack float2 loads (HBM stream starts at t=0); ds_write; barrier.
//   1. GEMV per wave: 8 iters x (1 ds_read_b128 + 3 coalesced float4 W loads
//      + 12 fma), 18-shuffle reduce, softmax-3. W is L2-resident (384 KB).
//   2. distributed new_mask (2 bpermute), write.
//   3. new_stack in-place on sv + stores + gate partials.
//   4. merge-butterfly reduce-scatter (17 shfl) -> distributed masked
//      softmax (8 shfl, 1 exp) -> 16 bpermute broadcast -> weighted sum,
//      residual, out store.
// ---------------------------------------------------------------------------
__global__ __launch_bounds__(512, 4) void stack_fused(
    const float* __restrict__ hidden,     // [4096][2048]
    const float* __restrict__ stack,      // [4096][16][16][128]
    const float* __restrict__ mask,       // [4096][16][16]
    const float* __restrict__ W_action,   // [48][2048]
    const float* __restrict__ b_action,   // [48]
    const float* __restrict__ W_gate,     // [128]
    const float* __restrict__ b_gate,     // [1]
    const float* __restrict__ res_weight, // [1]
    float* __restrict__ out,              // [4096][2048]
    float* __restrict__ new_stack,        // [4096][16][16][128]
    float* __restrict__ new_mask)         // [4096][16][16]
{
    __shared__ float hid[Hc]; // 8 KB

    const int bs   = blockIdx.x >> 1;
    const int half = blockIdx.x & 1;
    const int tid  = threadIdx.x;
    const int lane = tid & 63;
    const int wave = tid >> 6;
    const int n    = half * 8 + wave;

    // ---- phase 0: staging load + stack stream issue ----
    const float4* hrow4 = (const float4*)(hidden + (size_t)bs * Hc);
    float4 hstage = hrow4[tid]; // 512 thr x 16B = 8 KB

    const size_t sbase = ((size_t)bs * NHc + n) * (size_t)(SLOTSc * HDc);
    const float2* st2  = (const float2*)(stack + sbase);
    float2 sv[SLOTSc];
    #pragma unroll
    for (int k = 0; k < SLOTSc; ++k) sv[k] = st2[k * 64 + lane];

    const int cls = lane & 15;
    const int grp = lane & 48;
    float m_d = mask[((size_t)bs * NHc + n) * SLOTSc + cls];
    float2 wg = *(const float2*)(W_gate + 2 * lane);

    ((float4*)hid)[tid] = hstage;
    __syncthreads();

    // ---- phase 1: GEMV (vectorized) ----
    float s0 = 0.f, s1 = 0.f, s2 = 0.f;
    {
        const float4* hl = (const float4*)hid;
        const float4* W0 = (const float4*)(W_action + (size_t)(3 * n) * Hc);
        const float4* W1 = W0 + (Hc / 4);
        const float4* W2 = W1 + (Hc / 4);
        #pragma unroll 2
        for (int j = 0; j < 8; ++j) {
            float4 a  = hl[lane + j * 64];
            float4 b0 = W0[lane + j * 64];
            float4 b1 = W1[lane + j * 64];
            float4 b2 = W2[lane + j * 64];
            s0 = fmaf(a.x, b0.x, fmaf(a.y, b0.y, fmaf(a.z, b0.z, fmaf(a.w, b0.w, s0))));
            s1 = fmaf(a.x, b1.x, fmaf(a.y, b1.y, fmaf(a.z, b1.z, fmaf(a.w, b1.w, s1))));
            s2 = fmaf(a.x, b2.x, fmaf(a.y, b2.y, fmaf(a.z, b2.z, fmaf(a.w, b2.w, s2))));
        }
    }
    #pragma unroll
    for (int o = 32; o; o >>= 1) {
        s0 += __shfl_xor(s0, o, 64);
        s1 += __shfl_xor(s1, o, 64);
        s2 += __shfl_xor(s2, o, 64);
    }
    const float scale = 0.08838834764831845f; // 1/sqrt(128)
    float l0 = (s0 + b_action[3 * n + 0]) * scale;
    float l1 = (s1 + b_action[3 * n + 1]) * scale;
    float l2 = (s2 + b_action[3 * n + 2]) * scale;
    float lm = fmaxf(l0, fmaxf(l1, l2));
    float e0 = __expf(l0 - lm), e1 = __expf(l1 - lm), e2 = __expf(l2 - lm);
    float inv3 = 1.f / (e0 + e1 + e2);
    const float a_push = e0 * inv3;
    const float a_pop  = e1 * inv3;
    const float a_stay = e2 * inv3;

    float2 kv = *(const float2*)(hid + n * HDc + 2 * lane);

    // ---- phase 2: distributed new_mask ----
    {
        int ap_prev = (grp | (cls == 0 ? 0 : cls - 1)) << 2;
        int ap_next = (grp | (cls == 15 ? 15 : cls + 1)) << 2;
        float m_prev = __int_as_float(__builtin_amdgcn_ds_bpermute(ap_prev, __float_as_int(m_d)));
        float m_next = __int_as_float(__builtin_amdgcn_ds_bpermute(ap_next, __float_as_int(m_d)));
        m_prev = (cls == 0)  ? 1.f : m_prev;
        m_next = (cls == 15) ? 0.f : m_next;
        m_d = a_push * m_prev + a_pop * m_next + a_stay * m_d;  // now new_mask
    }
    if (lane < SLOTSc)
        new_mask[((size_t)bs * NHc + n) * SLOTSc + lane] = m_d;

    // ---- phase 3: new_stack (in-place on sv) + stores + gate partials ----
    const float bg = b_gate[0];
    const float rw = res_weight[0];
    float2* nst2 = (float2*)(new_stack + sbase);
    float p[SLOTSc];
    {
        float2 prev = kv;
        #pragma unroll
        for (int k = 0; k < SLOTSc; ++k) {
            float2 cur = sv[k];
            float2 nxt;
            if (k < SLOTSc - 1) nxt = sv[k + 1];
            else { nxt.x = 0.f; nxt.y = 0.f; }
            float2 ns;
            ns.x = a_push * prev.x + a_pop * nxt.x + a_stay * cur.x;
            ns.y = a_push * prev.y + a_pop * nxt.y + a_stay * cur.y;
            sv[k] = ns;
            nst2[k * 64 + lane] = ns;
            p[k] = ns.x * wg.x + ns.y * wg.y;
            prev = cur;
        }
    }

    // ---- phase 4a: merge-butterfly reduce-scatter (slot k -> lane&15==k) ----
    float w8[8];
    #pragma unroll
    for (int j = 0; j < 8; ++j) {
        float a = p[2 * j], b = p[2 * j + 1];
        bool hi = (lane & 1);
        float keep = hi ? b : a;
        float send = hi ? a : b;
        w8[j] = keep + __shfl_xor(send, 1, 64);
    }
    float w4[4];
    #pragma unroll
    for (int j = 0; j < 4; ++j) {
        float a = w8[2 * j], b = w8[2 * j + 1];
        bool hi = (lane & 2);
        float keep = hi ? b : a;
        float send = hi ? a : b;
        w4[j] = keep + __shfl_xor(send, 2, 64);
    }
    float w2[2];
    #pragma unroll
    for (int j = 0; j < 2; ++j) {
        float a = w4[2 * j], b = w4[2 * j + 1];
        bool hi = (lane & 4);
        float keep = hi ? b : a;
        float send = hi ? a : b;
        w2[j] = keep + __shfl_xor(send, 4, 64);
    }
    float u;
    {
        float a = w2[0], b = w2[1];
        bool hi = (lane & 8);
        float keep = hi ? b : a;
        float send = hi ? a : b;
        u = keep + __shfl_xor(send, 8, 64);
    }
    u += __shfl_xor(u, 16, 64);
    u += __shfl_xor(u, 32, 64);

    // ---- phase 4b: distributed masked softmax over 16 slots ----
    float g = u + bg + (1.f - m_d) * -1000000000.0f;
    float mx = g;
    mx = fmaxf(mx, __shfl_xor(mx, 1, 64));
    mx = fmaxf(mx, __shfl_xor(mx, 2, 64));
    mx = fmaxf(mx, __shfl_xor(mx, 4, 64));
    mx = fmaxf(mx, __shfl_xor(mx, 8, 64));
    float e = __expf(g - mx);
    float ssum = e;
    ssum += __shfl_xor(ssum, 1, 64);
    ssum += __shfl_xor(ssum, 2, 64);
    ssum += __shfl_xor(ssum, 4, 64);
    ssum += __shfl_xor(ssum, 8, 64);
    float gw_d = e / ssum;   // gate weight for slot l&15

    // ---- phase 4c: broadcast gate weights; weighted sum + residual ----
    float2 mo; mo.x = 0.f; mo.y = 0.f;
    const int grpb = grp << 2;
    #pragma unroll
    for (int k = 0; k < SLOTSc; ++k) {
        float gwk = __int_as_float(
            __builtin_amdgcn_ds_bpermute(grpb | (k << 2), __float_as_int(gw_d)));
        mo.x = fmaf(gwk, sv[k].x, mo.x);
        mo.y = fmaf(gwk, sv[k].y, mo.y);
    }
    float2 ov;
    ov.x = mo.x * rw + kv.x;
    ov.y = mo.y * rw + kv.y;
    *(float2*)(out + (size_t)bs * Hc + n * HDc + 2 * lane) = ov;
}

extern "C" void kernel_launch(void* const* d_in, const int* in_sizes, int n_in,
                              void* d_out, int out_size, void* d_ws, size_t ws_size,
                              hipStream_t stream) {
    const float* hidden     = (const float*)d_in[0];
    const float* stack      = (const float*)d_in[1];
    const float* mask       = (const float*)d_in[2];
    const float* W_action   = (const float*)d_in[3];
    const float* b_action   = (const float*)d_in[4];
    const float* W_gate     = (const float*)d_in[5];
    const float* b_gate     = (const float*)d_in[6];
    const float* res_weight = (const float*)d_in[7];

    float* out       = (float*)d_out;
    float* new_stack = out + (size_t)Bc * Sc * Hc;
    float* new_mask  = new_stack + (size_t)Bc * Sc * NHc * SLOTSc * HDc;

    hipLaunchKernelGGL(stack_fused, dim3(NROWS * 2), dim3(512), 0, stream,
                       hidden, stack, mask, W_action, b_action,
                       W_gate, b_gate, res_weight,
                       out, new_stack, new_mask);
}